// Round 3
// baseline (9913.837 us; speedup 1.0000x reference)
//
#include <hip/hip_runtime.h>

#define SEQ   8192
#define VOCAB 128000
#define L     64
#define NCH   128   // SEQ / L

// ws layout (float offsets)
#define OFF_WT   0          // WT[k][v]   : [20][128000] transposed W_i2o (10.24 MB)
#define OFF_CMB  2560000    // CmbT[k][t] : [20][8192] combined, k-major (640 KB)
#define OFF_CVEC 2723840    // cvecT[k][m][i] : [64][128][10]
#define OFF_AMAX 2805760    // amax[t] : 8192 x u64 packed (key<<32 | VOCAB-idx)
// total = 2,822,144 floats = 11.3 MB

// ---------------------------------------------------------------------------
// K1: gather embeddings -> CmbT rows 0..9; cvec_t = W_i2h[:,:10]*w_t + b_i2h;
//     zero the atomic-argmax array.
// ---------------------------------------------------------------------------
__global__ void k_embed(const int* __restrict__ ix, const float* __restrict__ emb,
                        const float* __restrict__ Wih, const float* __restrict__ bih,
                        float* __restrict__ ws) {
    int t = blockIdx.x * blockDim.x + threadIdx.x;
    if (t >= SEQ) return;

    ((unsigned long long*)(ws + OFF_AMAX))[t] = 0ULL;   // zero packed argmax

    int id = ix[t];
    float w[10];
    const float2* ep = (const float2*)(emb + (long long)id * 10);
#pragma unroll
    for (int j = 0; j < 5; j++) ((float2*)w)[j] = ep[j];

    // CmbT[j][t] = w[j]  (coalesced: consecutive t -> consecutive addr)
#pragma unroll
    for (int j = 0; j < 10; j++) ws[OFF_CMB + j * SEQ + t] = w[j];

    int m = t >> 6, k = t & 63;
    float* cv = ws + OFF_CVEC + (k * NCH + m) * 10;
#pragma unroll
    for (int i = 0; i < 10; i++) {
        float s = bih[i];
#pragma unroll
        for (int j = 0; j < 10; j++) s += Wih[i * 20 + j] * w[j];
        cv[i] = s;
    }
}

// ---------------------------------------------------------------------------
// K2: transpose W_i2o (VOCAB x 20) -> WT (20 x VOCAB)
// ---------------------------------------------------------------------------
__global__ void k_transpose(const float* __restrict__ Wio, float* __restrict__ ws) {
    int v = blockIdx.x * blockDim.x + threadIdx.x;
    if (v >= VOCAB) return;
    const float4* r = (const float4*)(Wio + (long long)v * 20);
    float vals[20];
#pragma unroll
    for (int q = 0; q < 5; q++) ((float4*)vals)[q] = r[q];
    float* WT = ws + OFF_WT;
#pragma unroll
    for (int k = 0; k < 20; k++) WT[k * VOCAB + v] = vals[k];
}

// ---------------------------------------------------------------------------
// K3: blocked scan of h_{t+1} = A h_t + c_t; writes h_t into CmbT rows 10..19
// ---------------------------------------------------------------------------
__global__ void k_scan(const float* __restrict__ Wih, float* __restrict__ ws) {
    __shared__ float P[100], Q[100];
    __shared__ float Dl[NCH][10];
    __shared__ float Hst[NCH][10];
    __shared__ float Hl[10];
    int tid = threadIdx.x;

    float Ar[10][10];
#pragma unroll
    for (int i = 0; i < 10; i++)
#pragma unroll
        for (int j = 0; j < 10; j++) Ar[i][j] = Wih[i * 20 + 10 + j];

    // ---- phase A: each thread = one chunk, from zero state ----
    {
        int m = tid;
        float h[10];
#pragma unroll
        for (int i = 0; i < 10; i++) h[i] = 0.f;
        const float* cvb = ws + OFF_CVEC;
        for (int k = 0; k < L; k++) {
            const float* c = cvb + (k * NCH + m) * 10;
            float nh[10];
#pragma unroll
            for (int i = 0; i < 10; i++) {
                float s = c[i];
#pragma unroll
                for (int j = 0; j < 10; j++) s += Ar[i][j] * h[j];
                nh[i] = s;
            }
#pragma unroll
            for (int i = 0; i < 10; i++) h[i] = nh[i];
        }
#pragma unroll
        for (int i = 0; i < 10; i++) Dl[m][i] = h[i];
    }

    // ---- phase B1: A^64 via 6 squarings ----
    if (tid < 100) P[tid] = Wih[(tid / 10) * 20 + 10 + (tid % 10)];
    __syncthreads();
    for (int it = 0; it < 6; it++) {
        if (tid < 100) {
            int i = tid / 10, j = tid % 10;
            float s = 0.f;
#pragma unroll
            for (int k = 0; k < 10; k++) s += P[i * 10 + k] * P[k * 10 + j];
            Q[tid] = s;
        }
        __syncthreads();
        if (tid < 100) P[tid] = Q[tid];
        __syncthreads();
    }

    // ---- phase B2: chunk-boundary scan (lanes 0..9, wave-lockstep) ----
    if (tid < 10) Hl[tid] = 0.f;
    __syncthreads();
    if (tid < 10) {
        int i = tid;
        float a64[10];
#pragma unroll
        for (int j = 0; j < 10; j++) a64[j] = P[i * 10 + j];
        float hc = 0.f;
        for (int m = 0; m < NCH; m++) {
            Hst[m][i] = hc;
            float s = Dl[m][i];
#pragma unroll
            for (int j = 0; j < 10; j++) s += a64[j] * Hl[j];
            Hl[i] = s;
            hc = s;
        }
    }
    __syncthreads();

    // ---- phase C: re-run with true starts; CmbT[10+i][m*64+k] = h_t ----
    {
        int m = tid;
        float h[10];
#pragma unroll
        for (int i = 0; i < 10; i++) h[i] = Hst[m][i];
        const float* cvb = ws + OFF_CVEC;
        for (int k = 0; k < L; k++) {
            int tg = m * 64 + k;
#pragma unroll
            for (int i = 0; i < 10; i++) ws[OFF_CMB + (10 + i) * SEQ + tg] = h[i];
            const float* c = cvb + (k * NCH + m) * 10;
            float nh[10];
#pragma unroll
            for (int i = 0; i < 10; i++) {
                float s = c[i];
#pragma unroll
                for (int j = 0; j < 10; j++) s += Ar[i][j] * h[j];
                nh[i] = s;
            }
#pragma unroll
            for (int i = 0; i < 10; i++) h[i] = nh[i];
        }
    }
}

// ---------------------------------------------------------------------------
// K4: fused logits + argmax, W staged in LDS.
// Grid: 500 blocks = 250 v-slices (512 v) x 2 t-halves (4096 t).
// Block: 256 threads = 4 waves; wave tg handles t-subrange tg*16..+15 of each
// 64-t pass; lane vt owns v = {sl*512+4vt..+3} u {sl*512+256+4vt..+3}.
// c (combined) double-buffered in LDS with register prefetch; one barrier/pass.
// Argmax merged globally via packed u64 atomicMax (exact jnp.argmax semantics).
// ---------------------------------------------------------------------------
__global__ __launch_bounds__(256, 2)
void k_logits(const float* __restrict__ ws, const float* __restrict__ bio,
              unsigned long long* __restrict__ amax) {
    __shared__ float Wl[20 * 512];        // 40 KB
    __shared__ float c2[2][20 * 64];      // 10 KB double-buffered combined

    int tid = threadIdx.x;
    int vt  = tid & 63;
    int tg  = tid >> 6;

    int b     = blockIdx.x;
    int sl    = b % 250;                  // v-slice
    int th    = b / 250;                  // t-half
    int tbase = th * 4096;

    const float4* WT4   = (const float4*)(ws + OFF_WT);
    const float4* CMB4  = (const float4*)(ws + OFF_CMB);
    const float4* B4    = (const float4*)bio;
    float4* Wl4 = (float4*)Wl;

    // ---- stage W slice: 2560 float4, 10 per thread (flat copy) ----
#pragma unroll
    for (int r = 0; r < 10; r++) {
        int F = tid + 256 * r;            // = k*128 + j
        int k = F >> 7, j = F & 127;
        Wl4[F] = WT4[k * 32000 + sl * 128 + j];
    }

    // ---- stage c for pass 0 ----
    {
        int tb4 = tbase >> 2;
        float4* dst = (float4*)&c2[0][0];
        int k = tid >> 4, j = tid & 15;
        dst[tid] = CMB4[k * 2048 + tb4 + j];
        if (tid < 64) {
            int F = 256 + tid;
            int k2 = F >> 4, j2 = F & 15;
            dst[F] = CMB4[k2 * 2048 + tb4 + j2];
        }
    }
    __syncthreads();

    // bias for this thread's 8 v
    float4 b4a = B4[sl * 128 + vt];
    float4 b4b = B4[sl * 128 + 64 + vt];
    int v0a = sl * 512 + 4 * vt;
    int v0b = v0a + 256;

    int cur = 0;
    for (int p = 0; p < 64; p++) {
        // ---- prefetch c for pass p+1 into registers ----
        int pn = (p + 1 < 64) ? p + 1 : 63;
        int tb4n = (tbase + pn * 64) >> 2;
        float4 pre0, pre1;
        {
            int k = tid >> 4, j = tid & 15;
            pre0 = CMB4[k * 2048 + tb4n + j];
        }
        if (tid < 64) {
            int F = 256 + tid;
            int k2 = F >> 4, j2 = F & 15;
            pre1 = CMB4[k2 * 2048 + tb4n + j2];
        }

        // ---- compute pass p ----
        float acc[16][8];
#pragma unroll
        for (int t = 0; t < 16; t++) {
            acc[t][0] = b4a.x; acc[t][1] = b4a.y; acc[t][2] = b4a.z; acc[t][3] = b4a.w;
            acc[t][4] = b4b.x; acc[t][5] = b4b.y; acc[t][6] = b4b.z; acc[t][7] = b4b.w;
        }
        const float* cb = &c2[cur][0];
#pragma unroll
        for (int k = 0; k < 20; k++) {
            float4 w0 = Wl4[k * 128 + vt];
            float4 w1 = Wl4[k * 128 + 64 + vt];
            const float4* cp = (const float4*)(cb + k * 64 + tg * 16);
            float cvv[16];
            ((float4*)cvv)[0] = cp[0]; ((float4*)cvv)[1] = cp[1];
            ((float4*)cvv)[2] = cp[2]; ((float4*)cvv)[3] = cp[3];
#pragma unroll
            for (int t = 0; t < 16; t++) {
                acc[t][0] += cvv[t] * w0.x;
                acc[t][1] += cvv[t] * w0.y;
                acc[t][2] += cvv[t] * w0.z;
                acc[t][3] += cvv[t] * w0.w;
                acc[t][4] += cvv[t] * w1.x;
                acc[t][5] += cvv[t] * w1.y;
                acc[t][6] += cvv[t] * w1.z;
                acc[t][7] += cvv[t] * w1.w;
            }
        }

        // ---- local + cross-lane argmax, one atomic per (wave, t) ----
        int tb = tbase + p * 64 + tg * 16;
#pragma unroll
        for (int t = 0; t < 16; t++) {
            float bv = acc[t][0]; int bi = v0a;
#pragma unroll
            for (int j = 1; j < 4; j++)
                if (acc[t][j] > bv) { bv = acc[t][j]; bi = v0a + j; }
#pragma unroll
            for (int j = 4; j < 8; j++)
                if (acc[t][j] > bv) { bv = acc[t][j]; bi = v0b + j - 4; }
            for (int off = 32; off > 0; off >>= 1) {
                float ov = __shfl_down(bv, off);
                int   oi = __shfl_down(bi, off);
                if (ov > bv || (ov == bv && oi < bi)) { bv = ov; bi = oi; }
            }
            if (vt == 0) {
                unsigned int u = __float_as_uint(bv);
                unsigned int key = (u & 0x80000000u) ? ~u : (u | 0x80000000u);
                unsigned long long packed =
                    ((unsigned long long)key << 32) | (unsigned int)(VOCAB - bi);
                atomicMax(&amax[tb + t], packed);
            }
        }

        // ---- write prefetched c to the other buffer; swap ----
        int nxt = cur ^ 1;
        {
            float4* dst = (float4*)&c2[nxt][0];
            dst[tid] = pre0;
            if (tid < 64) dst[256 + tid] = pre1;
        }
        __syncthreads();
        cur = nxt;
    }
}

// ---------------------------------------------------------------------------
// K5: unpack argmax -> float index
// ---------------------------------------------------------------------------
__global__ void k_out(const unsigned long long* __restrict__ amax,
                      float* __restrict__ out) {
    int t = blockIdx.x * blockDim.x + threadIdx.x;
    if (t >= SEQ) return;
    unsigned long long p = amax[t];
    int idx = VOCAB - (int)(p & 0xFFFFFFFFu);
    out[t] = (float)idx;
}

// ---------------------------------------------------------------------------
extern "C" void kernel_launch(void* const* d_in, const int* in_sizes, int n_in,
                              void* d_out, int out_size, void* d_ws, size_t ws_size,
                              hipStream_t stream) {
    (void)in_sizes; (void)n_in; (void)out_size; (void)ws_size;
    const int*   ix  = (const int*)d_in[0];
    const float* emb = (const float*)d_in[1];
    const float* Wih = (const float*)d_in[2];
    const float* bih = (const float*)d_in[3];
    const float* Wio = (const float*)d_in[4];
    const float* bio = (const float*)d_in[5];
    float* out = (float*)d_out;
    float* ws  = (float*)d_ws;
    unsigned long long* amax = (unsigned long long*)(ws + OFF_AMAX);

    hipLaunchKernelGGL(k_embed,     dim3(SEQ / 256), dim3(256), 0, stream, ix, emb, Wih, bih, ws);
    hipLaunchKernelGGL(k_transpose, dim3(VOCAB / 256), dim3(256), 0, stream, Wio, ws);
    hipLaunchKernelGGL(k_scan,      dim3(1), dim3(128), 0, stream, Wih, ws);
    hipLaunchKernelGGL(k_logits,    dim3(500), dim3(256), 0, stream, ws, bio, amax);
    hipLaunchKernelGGL(k_out,       dim3(SEQ / 256), dim3(256), 0, stream, amax, out);
}